// Round 8
// baseline (108.608 us; speedup 1.0000x reference)
//
#include <hip/hip_runtime.h>
#include <hip/hip_bf16.h>
#include <cstdint>
#include <cstddef>

#define EPS 1e-5f
#define NEG 0.2f

static constexpr int B_ = 8, N_ = 4096, K_ = 20, M_ = B_ * N_;  // M = 32768

typedef __attribute__((ext_vector_type(8))) _Float16 f16x8;
typedef __attribute__((ext_vector_type(4))) float f32x4;

// async global->LDS, 16B per lane; LDS dest = wave-uniform base + lane*16
__device__ __forceinline__ void gload_lds16(const _Float16* g, _Float16* l) {
  __builtin_amdgcn_global_load_lds(
      (const __attribute__((address_space(1))) uint32_t*)g,
      (__attribute__((address_space(3))) uint32_t*)l, 16, 0, 0);
}

// ---------------- prep + layer-1 C=3 GEMM, one kernel ------------------------
// blocks 0..511: gemm_c3 ; 512..1327: weight fold ; 1328: BN param table
__global__ __launch_bounds__(256) void prep_c3(
    const float* __restrict__ x, const float* __restrict__ w1,
    const float* __restrict__ w2, const float* __restrict__ w3,
    const float* __restrict__ w4, const float* __restrict__ w5,
    const float* __restrict__ w6,
    const float* __restrict__ g1, const float* __restrict__ b1, const float* __restrict__ m1, const float* __restrict__ v1,
    const float* __restrict__ g2, const float* __restrict__ b2, const float* __restrict__ m2, const float* __restrict__ v2,
    const float* __restrict__ g3, const float* __restrict__ b3, const float* __restrict__ m3, const float* __restrict__ v3,
    const float* __restrict__ g4, const float* __restrict__ b4, const float* __restrict__ m4, const float* __restrict__ v4,
    const float* __restrict__ g5, const float* __restrict__ b5, const float* __restrict__ m5, const float* __restrict__ v5,
    const float* __restrict__ g6, const float* __restrict__ b6, const float* __restrict__ m6, const float* __restrict__ v6,
    float* __restrict__ P, _Float16* __restrict__ Wh, _Float16* __restrict__ z) {
  const int bid = blockIdx.x, tid = threadIdx.x;
  if (bid < 512) {
    const int o  = tid & 63;
    const int pi = tid >> 6;
    const float ww0 = w1[o * 3 + 0], ww1 = w1[o * 3 + 1], ww2 = w1[o * 3 + 2];
    const float iv = g1[o] * rsqrtf(v1[o] + EPS);
    const int pbase = bid * 64;
    const int b = pbase >> 12;
    const int nbase = pbase & (N_ - 1);
    const float* xb = x + (size_t)b * 3 * N_;
    for (int pj = pi; pj < 64; pj += 4) {
      const int n = nbase + pj;
      const float x0 = xb[n], x1v = xb[N_ + n], x2v = xb[2 * N_ + n];
      z[(size_t)(pbase + pj) * 64 + o] = (_Float16)((x0 * ww0 + x1v * ww1 + x2v * ww2) * iv);
    }
    return;
  }
  if (bid == 1328) {
    const float* G[6]  = {g1, g2, g3, g4, g5, g6};
    const float* Bb[6] = {b1, b2, b3, b4, b5, b6};
    const float* Mm[6] = {m1, m2, m3, m4, m5, m6};
    const float* Vv[6] = {v1, v2, v3, v4, v5, v6};
    const int Cs[6] = {64, 64, 128, 256, 256, 128};
    const int OI[6] = {0, 128, 256, 512, 1024, 1536};
    const int OB[6] = {64, 192, 384, 768, 1280, 1664};
    for (int l = 0; l < 6; ++l) {
      for (int c = tid; c < Cs[l]; c += 256) {
        float iv = G[l][c] * rsqrtf(Vv[l][c] + EPS);
        P[OI[l] + c] = iv;
        P[OB[l] + c] = Bb[l][c] - Mm[l][c] * iv;
      }
    }
    return;
  }
  const int fb = bid - 512;
  const float* w; const float* g; const float* v; _Float16* dst; int lc, base;
  if (fb < 16)       { w = w2; g = g2; v = v2; dst = Wh + 0;      lc = 6; base = 0;   }
  else if (fb < 48)  { w = w3; g = g3; v = v3; dst = Wh + 4096;   lc = 6; base = 16;  }
  else if (fb < 176) { w = w4; g = g4; v = v4; dst = Wh + 12288;  lc = 7; base = 48;  }
  else if (fb < 688) { w = w5; g = g5; v = v5; dst = Wh + 45056;  lc = 9; base = 176; }
  else               { w = w6; g = g6; v = v6; dst = Wh + 176128; lc = 8; base = 688; }
  const int e = (fb - base) * 256 + tid;
  const int o = e >> lc;
  dst[e] = (_Float16)(w[e] * (g[o] * rsqrtf(v[o] + EPS)));
}

// ---------------- fused edge(C=64) + small GEMM ------------------------------
template <int BO>
__global__ __launch_bounds__(256) void edge_gemm64(
    const _Float16* __restrict__ z, const int* __restrict__ idx,
    const float* __restrict__ betap,
    const _Float16* __restrict__ W,           // (BO, 64) inv-folded
    _Float16* __restrict__ hout,              // h512 column base (ld 512)
    _Float16* __restrict__ zout, int ldzout) {
  constexpr int GW = BO / 8;
  constexpr int OJ = BO / 32;
  __shared__ _Float16 Asmem[128 * 64];
  __shared__ _Float16 Wsmem[BO * 64];

  const int tid = threadIdx.x, lane = tid & 63, wid = tid >> 6;
  const int batch = blockIdx.x & 7, chunk = blockIdx.x >> 3;
  const int bm0 = (batch << 12) + chunk * 128;
  const int lr = lane & 15, lk = lane >> 4;

  const _Float16* Wbase = W + (size_t)lr * 64 + lk * 8;
#pragma unroll
  for (int g = wid; g < GW; g += 4) {
    const int o = g >> 1, s = g & 1;
    gload_lds16(Wbase + (size_t)16 * o * 64 + s * 32, Wsmem + g * 512);
  }

  const int lid = tid & 7, cb = lid * 8;
  float bt[8];
#pragma unroll
  for (int q = 0; q < 8; ++q) bt[q] = betap[cb + q];
  const _Float16* zb = z + ((size_t)(batch << 12)) * 64;
#pragma unroll
  for (int pass = 0; pass < 4; ++pass) {
    const int pi = pass * 32 + (tid >> 3);
    const int p = bm0 + pi;
    const int* ip = idx + (size_t)p * K_;
    const int ir0 = ip[lid];
    const int ir1 = ip[8 + lid];
    const int ir2 = ip[16 + (lid & 3)];
    f16x8 mx = *reinterpret_cast<const f16x8*>(zb + (size_t)__shfl(ir0, 0, 8) * 64 + cb);
#pragma unroll
    for (int k = 1; k < K_; ++k) {
      const int g = (k < 8) ? __shfl(ir0, k, 8)
                  : (k < 16) ? __shfl(ir1, k - 8, 8)
                             : __shfl(ir2, k - 16, 8);
      const f16x8 v = *reinterpret_cast<const f16x8*>(zb + (size_t)g * 64 + cb);
#pragma unroll
      for (int q = 0; q < 8; ++q) mx[q] = v[q] > mx[q] ? v[q] : mx[q];
    }
    const f16x8 vc = *reinterpret_cast<const f16x8*>(z + (size_t)p * 64 + cb);
    f16x8 vo;
#pragma unroll
    for (int q = 0; q < 8; ++q) {
      const float e = (float)mx[q] - (float)vc[q] + bt[q];
      vo[q] = (_Float16)fmaxf(e, NEG * e);
    }
    *reinterpret_cast<f16x8*>(hout + (size_t)p * 512 + cb) = vo;
    const int i = pi >> 4, rr = pi & 15, s = cb >> 5, kk = (cb >> 3) & 3;
    *reinterpret_cast<f16x8*>(Asmem + (i * 2 + s) * 512 + ((kk << 4) | rr) * 8) = vo;
  }
  __syncthreads();

  const int wr = wid >> 1, wc = wid & 1;
  f32x4 acc[4][OJ];
#pragma unroll
  for (int i = 0; i < 4; ++i)
#pragma unroll
    for (int j = 0; j < OJ; ++j) acc[i][j] = (f32x4){0.f, 0.f, 0.f, 0.f};
#pragma unroll
  for (int s = 0; s < 2; ++s) {
    f16x8 av[4], wv[OJ];
#pragma unroll
    for (int i = 0; i < 4; ++i)
      av[i] = *reinterpret_cast<const f16x8*>(Asmem + ((wr * 4 + i) * 2 + s) * 512 + lane * 8);
#pragma unroll
    for (int j = 0; j < OJ; ++j)
      wv[j] = *reinterpret_cast<const f16x8*>(Wsmem + ((wc * OJ + j) * 2 + s) * 512 + lane * 8);
#pragma unroll
    for (int i = 0; i < 4; ++i)
#pragma unroll
      for (int j = 0; j < OJ; ++j)
        acc[i][j] = __builtin_amdgcn_mfma_f32_16x16x32_f16(av[i], wv[j], acc[i][j], 0, 0, 0);
  }

#pragma unroll
  for (int j = 0; j < OJ; ++j) {
    const int o = wc * (BO / 2) + 16 * j + lr;
#pragma unroll
    for (int i = 0; i < 4; ++i) {
      const int r0 = bm0 + wr * 64 + 16 * i + lk * 4;
#pragma unroll
      for (int q = 0; q < 4; ++q)
        zout[(size_t)(r0 + q) * ldzout + o] = (_Float16)acc[i][j][q];
    }
  }
}

// ---------------- fused edge(C=128) + full-width GEMM (L3e + L4g) ------------
// Block = 128 points; edge over z3 (ld 128) -> x3 to h512 + LDS A-fragments;
// W4 (256x128, 64KB) staged async during edge; then 4-K-step GEMM, BO=256.
__global__ __launch_bounds__(256, 1) void edge_gemm_full(
    const _Float16* __restrict__ z, const int* __restrict__ idx,
    const float* __restrict__ betap,          // edge beta (128)
    const _Float16* __restrict__ W,           // (256, 128) inv-folded
    _Float16* __restrict__ hout,              // h512 + 128
    _Float16* __restrict__ zout) {            // z4, ld 256
  constexpr int CIN = 128, BO = 256;
  __shared__ _Float16 Asmem[128 * CIN];       // 32KB, 32 groups
  __shared__ _Float16 Wsmem[BO * CIN];        // 64KB, 64 groups

  const int tid = threadIdx.x, lane = tid & 63, wid = tid >> 6;
  const int batch = blockIdx.x & 7, chunk = blockIdx.x >> 3;
  const int bm0 = (batch << 12) + chunk * 128;
  const int lr = lane & 15, lk = lane >> 4;

  // stage W4: 64 groups; group g = ob*4 + kk (ob = o>>4, kk = K-step)
  const _Float16* Wbase = W + (size_t)lr * CIN + lk * 8;
#pragma unroll
  for (int g = wid; g < 64; g += 4) {
    const int ob = g >> 2, kk = g & 3;
    gload_lds16(Wbase + (size_t)16 * ob * CIN + kk * 32, Wsmem + g * 512);
  }

  // edge phase: 8 passes x 16 points; thread owns 8 channels (TPP=16)
  const int lid = tid & 15, cb = lid * 8;
  float bt[8];
#pragma unroll
  for (int q = 0; q < 8; ++q) bt[q] = betap[cb + q];
  const _Float16* zb = z + ((size_t)(batch << 12)) * CIN;
#pragma unroll
  for (int pass = 0; pass < 8; ++pass) {
    const int pi = pass * 16 + (tid >> 4);
    const int p = bm0 + pi;
    const int* ip = idx + (size_t)p * K_;
    const int ir0 = ip[lid];
    const int ir1 = ip[16 + (lid & 3)];
    f16x8 mx = *reinterpret_cast<const f16x8*>(zb + (size_t)__shfl(ir0, 0, 16) * CIN + cb);
#pragma unroll
    for (int k = 1; k < K_; ++k) {
      const int g = (k < 16) ? __shfl(ir0, k, 16) : __shfl(ir1, k - 16, 16);
      const f16x8 v = *reinterpret_cast<const f16x8*>(zb + (size_t)g * CIN + cb);
#pragma unroll
      for (int q = 0; q < 8; ++q) mx[q] = v[q] > mx[q] ? v[q] : mx[q];
    }
    const f16x8 vc = *reinterpret_cast<const f16x8*>(z + (size_t)p * CIN + cb);
    f16x8 vo;
#pragma unroll
    for (int q = 0; q < 8; ++q) {
      const float e = (float)mx[q] - (float)vc[q] + bt[q];
      vo[q] = (_Float16)fmaxf(e, NEG * e);
    }
    *reinterpret_cast<f16x8*>(hout + (size_t)p * 512 + cb) = vo;
    // A fragment: group (pi>>4)*4 + (lid>>2); lane = (lid&3)*16 + (pi&15)
    *reinterpret_cast<f16x8*>(Asmem + ((pi >> 4) * 4 + (lid >> 2)) * 512 +
                              (((lid & 3) << 4) | (pi & 15)) * 8) = vo;
  }
  __syncthreads();  // drains vmcnt (W stage) + lgkmcnt (A writes)

  // GEMM: 4 waves 2x2; per-wave 64 rows x 128 cols; MI=4, OJ=8, 4 K-steps
  const int wr = wid >> 1, wc = wid & 1;
  f32x4 acc[4][8];
#pragma unroll
  for (int i = 0; i < 4; ++i)
#pragma unroll
    for (int j = 0; j < 8; ++j) acc[i][j] = (f32x4){0.f, 0.f, 0.f, 0.f};
#pragma unroll
  for (int kk = 0; kk < 4; ++kk) {
    f16x8 av[4], wv[8];
#pragma unroll
    for (int i = 0; i < 4; ++i)
      av[i] = *reinterpret_cast<const f16x8*>(Asmem + ((wr * 4 + i) * 4 + kk) * 512 + lane * 8);
#pragma unroll
    for (int j = 0; j < 8; ++j)
      wv[j] = *reinterpret_cast<const f16x8*>(Wsmem + ((wc * 8 + j) * 4 + kk) * 512 + lane * 8);
#pragma unroll
    for (int i = 0; i < 4; ++i)
#pragma unroll
      for (int j = 0; j < 8; ++j)
        acc[i][j] = __builtin_amdgcn_mfma_f32_16x16x32_f16(av[i], wv[j], acc[i][j], 0, 0, 0);
  }

#pragma unroll
  for (int j = 0; j < 8; ++j) {
    const int o = wc * 128 + 16 * j + lr;
#pragma unroll
    for (int i = 0; i < 4; ++i) {
      const int r0 = bm0 + wr * 64 + 16 * i + lk * 4;
#pragma unroll
      for (int q = 0; q < 4; ++q)
        zout[(size_t)(r0 + q) * 256 + o] = (_Float16)acc[i][j][q];
    }
  }
}

// ---------------- fp16 MFMA GEMM, 4-buffer counted-vmcnt pipeline ------------
// MODE 1: lrelu(acc+beta)  MODE 2: MODE1 then fused dot w7
template <int BM, int BO, int C, int MODE>
__global__ __launch_bounds__(256, 1) void gemm_pipe(
    const _Float16* __restrict__ A, int lda,
    const _Float16* __restrict__ W,
    const float* __restrict__ betap,
    _Float16* __restrict__ out, int ldout,
    const float* __restrict__ w7, float* __restrict__ dout) {
  constexpr int NK = C / 32;
  constexpr int GA = BM / 16;
  constexpr int GW = BO / 16;
  constexpr int GT = GA + GW;
  constexpr int GP = GT / 4;
  constexpr int SB = (BM + BO) * 32;
  constexpr int MI = BM / 32, OJ = BO / 32;
  __shared__ _Float16 lds[4 * SB];

  const int lane = threadIdx.x & 63;
  const int wid  = threadIdx.x >> 6;
  const int wr = wid >> 1, wc = wid & 1;
  const int bm0 = blockIdx.x * BM;
  const int bo0 = blockIdx.y * BO;
  const int lr = lane & 15, lk = lane >> 4;

  const _Float16* Abase = A + (size_t)(bm0 + lr) * lda + lk * 8;
  const _Float16* Wbase = W + (size_t)(bo0 + lr) * C + lk * 8;

  f32x4 acc[MI][OJ];
#pragma unroll
  for (int i = 0; i < MI; ++i)
#pragma unroll
    for (int j = 0; j < OJ; ++j) acc[i][j] = (f32x4){0.f, 0.f, 0.f, 0.f};

  auto stage = [&](int buf, int k0) {
    _Float16* dst = &lds[buf * SB];
#pragma unroll
    for (int q = 0; q < GP; ++q) {
      const int g = wid * GP + q;
      const _Float16* src = (g < GA)
          ? Abase + (size_t)16 * g * lda + k0
          : Wbase + (size_t)16 * (g - GA) * C + k0;
      gload_lds16(src, dst + g * 512);
    }
  };

  auto compute = [&](int buf) {
    const _Float16* Ab = &lds[buf * SB];
    const _Float16* Wb = &lds[buf * SB + GA * 512];
    f16x8 av[MI], wv[OJ];
#pragma unroll
    for (int i = 0; i < MI; ++i)
      av[i] = *reinterpret_cast<const f16x8*>(Ab + (wr * MI + i) * 512 + lane * 8);
#pragma unroll
    for (int j = 0; j < OJ; ++j)
      wv[j] = *reinterpret_cast<const f16x8*>(Wb + (wc * OJ + j) * 512 + lane * 8);
#pragma unroll
    for (int i = 0; i < MI; ++i)
#pragma unroll
      for (int j = 0; j < OJ; ++j)
        acc[i][j] = __builtin_amdgcn_mfma_f32_16x16x32_f16(av[i], wv[j], acc[i][j], 0, 0, 0);
  };

  stage(0, 0);
  stage(1, 32);
#pragma unroll
  for (int t = 0; t < NK; ++t) {
    if (t + 2 < NK) {
      stage((t + 2) & 3, (t + 2) * 32);
      if constexpr (GP == 3)      asm volatile("s_waitcnt vmcnt(6)" ::: "memory");
      else if constexpr (GP == 4) asm volatile("s_waitcnt vmcnt(8)" ::: "memory");
      else                        asm volatile("s_waitcnt vmcnt(12)" ::: "memory");
    } else if (t + 1 < NK) {
      if constexpr (GP == 3)      asm volatile("s_waitcnt vmcnt(3)" ::: "memory");
      else if constexpr (GP == 4) asm volatile("s_waitcnt vmcnt(4)" ::: "memory");
      else                        asm volatile("s_waitcnt vmcnt(6)" ::: "memory");
    } else {
      asm volatile("s_waitcnt vmcnt(0)" ::: "memory");
    }
    __builtin_amdgcn_s_barrier();
    compute(t & 3);
  }

  if constexpr (MODE == 2) {
    __shared__ float dotbuf[BM][2];
    float rowdot[MI][4];
#pragma unroll
    for (int i = 0; i < MI; ++i)
#pragma unroll
      for (int q = 0; q < 4; ++q) rowdot[i][q] = 0.f;
#pragma unroll
    for (int j = 0; j < OJ; ++j) {
      const int o = wc * (BO / 2) + 16 * j + lr;
      const float bt = betap[o];
      const float wf = w7[o];
#pragma unroll
      for (int i = 0; i < MI; ++i)
#pragma unroll
        for (int q = 0; q < 4; ++q) {
          float t = acc[i][j][q] + bt;
          t = fmaxf(t, NEG * t);
          rowdot[i][q] += t * wf;
        }
    }
#pragma unroll
    for (int i = 0; i < MI; ++i)
#pragma unroll
      for (int q = 0; q < 4; ++q) {
#pragma unroll
        for (int off = 1; off < 16; off <<= 1)
          rowdot[i][q] += __shfl_xor(rowdot[i][q], off, 16);
        if (lr == 0) dotbuf[wr * (BM / 2) + 16 * i + lk * 4 + q][wc] = rowdot[i][q];
      }
    __syncthreads();
    if (threadIdx.x < BM) {
      const float s = dotbuf[threadIdx.x][0] + dotbuf[threadIdx.x][1];
      dout[bm0 + threadIdx.x] = fmaxf(s, NEG * s);
    }
    return;
  }

#pragma unroll
  for (int j = 0; j < OJ; ++j) {
    const int o = bo0 + wc * (BO / 2) + 16 * j + lr;
    const float bt = betap[o];
#pragma unroll
    for (int i = 0; i < MI; ++i) {
      const int r0 = bm0 + wr * (BM / 2) + 16 * i + lk * 4;
#pragma unroll
      for (int q = 0; q < 4; ++q) {
        float t = acc[i][j][q] + bt;
        t = fmaxf(t, NEG * t);
        out[(size_t)(r0 + q) * ldout + o] = (_Float16)t;
      }
    }
  }
}

// ---------------- edge max, standalone (O=256) -------------------------------
template <int O>
__global__ __launch_bounds__(256) void edge_max8(
    const _Float16* __restrict__ z, const int* __restrict__ idx,
    const float* __restrict__ betap, _Float16* __restrict__ out, int ldout) {
  constexpr int TPP = O / 8;
  constexpr int PPB = 256 / TPP;
  constexpr int NW = (K_ + TPP - 1) / TPP;
  const int t = threadIdx.x;
  const int batch = blockIdx.x & 7;
  const int chunk = blockIdx.x >> 3;
  const int p = (batch << 12) + chunk * PPB + t / TPP;
  const int lid = t % TPP;
  const int cb = lid * 8;
  const int* ip = idx + (size_t)p * K_;
  int ir[NW];
#pragma unroll
  for (int wv = 0; wv < NW; ++wv) {
    const int l = wv * TPP + lid;
    ir[wv] = (l < K_) ? ip[l] : ip[0];
  }
  const _Float16* zb = z + ((size_t)(batch << 12)) * O;

  f16x8 mx = *reinterpret_cast<const f16x8*>(zb + (size_t)__shfl(ir[0], 0, TPP) * O + cb);
#pragma unroll
  for (int k = 1; k < K_; ++k) {
    const int g = __shfl(ir[k / TPP], k % TPP, TPP);
    const f16x8 v = *reinterpret_cast<const f16x8*>(zb + (size_t)g * O + cb);
#pragma unroll
    for (int q = 0; q < 8; ++q) mx[q] = v[q] > mx[q] ? v[q] : mx[q];
  }
  const f16x8 vc = *reinterpret_cast<const f16x8*>(z + (size_t)p * O + cb);
  f16x8 vo;
#pragma unroll
  for (int q = 0; q < 8; ++q) {
    const float e = (float)mx[q] - (float)vc[q] + betap[cb + q];
    vo[q] = (_Float16)fmaxf(e, NEG * e);
  }
  *reinterpret_cast<f16x8*>(out + (size_t)p * ldout + cb) = vo;
}

// ---------------- launch -----------------------------------------------------
extern "C" void kernel_launch(void* const* d_in, const int* in_sizes, int n_in,
                              void* d_out, int out_size, void* d_ws, size_t ws_size,
                              hipStream_t stream) {
  const float* x  = (const float*)d_in[0];
  const int* idx  = (const int*)d_in[1];
  const float* w[7];
  for (int i = 0; i < 7; ++i) w[i] = (const float*)d_in[2 + i];
  const float* bn[24];
  for (int i = 0; i < 24; ++i) bn[i] = (const float*)d_in[9 + i];

  // ws: P@0 (32KB) | Wh@32KB (~0.42MB) | z_a@1MB (16MB) | h512@17MB (32MB) | z_b@49MB (16MB)
  float* P       = (float*)d_ws;
  _Float16* Wh   = (_Float16*)((char*)d_ws + (32 << 10));
  _Float16* z_a  = (_Float16*)((char*)d_ws + (1u << 20));
  _Float16* h512 = (_Float16*)((char*)d_ws + (17u << 20));
  _Float16* z_b  = (_Float16*)((char*)d_ws + (49u << 20));

  prep_c3<<<1329, 256, 0, stream>>>(
      x, w[0], w[1], w[2], w[3], w[4], w[5],
      bn[0], bn[1], bn[2], bn[3],   bn[4], bn[5], bn[6], bn[7],
      bn[8], bn[9], bn[10], bn[11], bn[12], bn[13], bn[14], bn[15],
      bn[16], bn[17], bn[18], bn[19], bn[20], bn[21], bn[22], bn[23],
      P, Wh, z_a);

  const float* bt1 = P + 64;
  const float* bt2 = P + 192;
  const float* bt3 = P + 384;
  const float* bt4 = P + 768;
  const float* bt5 = P + 1280;
  const float* bt6 = P + 1664;
  const _Float16* W2 = Wh + 0, *W3 = Wh + 4096, *W4 = Wh + 12288,
               *W5 = Wh + 45056, *W6 = Wh + 176128;

  // L1 edge + L2 GEMM fused: z1 -> (x1 -> h512+0, z2 -> z_b ld 64)
  edge_gemm64<64><<<M_ / 128, 256, 0, stream>>>(z_a, idx, bt1, W2, h512 + 0, z_b, 64);
  // L2 edge + L3 GEMM fused: z2 -> (x2 -> h512+64, z3 -> z_a ld 128)
  edge_gemm64<128><<<M_ / 128, 256, 0, stream>>>(z_b, idx, bt2, W3, h512 + 64, z_a, 128);
  // L3 edge + L4 GEMM fused: z3 -> (x3 -> h512+128, z4 -> z_b ld 256)
  edge_gemm_full<<<M_ / 128, 256, 0, stream>>>(z_a, idx, bt3, W4, h512 + 128, z_b);
  // L4 edge: z4 -> x4 (h512+256)
  edge_max8<256><<<M_ / 8, 256, 0, stream>>>(z_b, idx, bt4, h512 + 256, 512);
  // L5: pointconv(512 -> 256), BO=256 single-y -> z_a ld 256
  gemm_pipe<128, 256, 512, 1><<<dim3(M_ / 128, 1), 256, 0, stream>>>(
      h512, 512, W5, bt5, z_a, 256, nullptr, nullptr);
  // L6+L7: pointconv(256 -> 128) fused with final 128 -> 1 + lrelu
  gemm_pipe<64, 128, 256, 2><<<dim3(M_ / 64, 1), 256, 0, stream>>>(
      z_a, 256, W6, bt6, nullptr, 0, w[6], (float*)d_out);
}

// Round 9
// 107.614 us; speedup vs baseline: 1.0092x; 1.0092x over previous
//
#include <hip/hip_runtime.h>
#include <hip/hip_bf16.h>
#include <cstdint>
#include <cstddef>

#define EPS 1e-5f
#define NEG 0.2f

static constexpr int B_ = 8, N_ = 4096, K_ = 20, M_ = B_ * N_;  // M = 32768

typedef __attribute__((ext_vector_type(8))) _Float16 f16x8;
typedef __attribute__((ext_vector_type(4))) float f32x4;

// async global->LDS, 16B per lane; LDS dest = wave-uniform base + lane*16
__device__ __forceinline__ void gload_lds16(const _Float16* g, _Float16* l) {
  __builtin_amdgcn_global_load_lds(
      (const __attribute__((address_space(1))) uint32_t*)g,
      (__attribute__((address_space(3))) uint32_t*)l, 16, 0, 0);
}

// ---------------- prep + layer-1 C=3 GEMM, one kernel ------------------------
// blocks 0..511: gemm_c3 ; 512..1327: weight fold ; 1328: BN param table
__global__ __launch_bounds__(256) void prep_c3(
    const float* __restrict__ x, const float* __restrict__ w1,
    const float* __restrict__ w2, const float* __restrict__ w3,
    const float* __restrict__ w4, const float* __restrict__ w5,
    const float* __restrict__ w6,
    const float* __restrict__ g1, const float* __restrict__ b1, const float* __restrict__ m1, const float* __restrict__ v1,
    const float* __restrict__ g2, const float* __restrict__ b2, const float* __restrict__ m2, const float* __restrict__ v2,
    const float* __restrict__ g3, const float* __restrict__ b3, const float* __restrict__ m3, const float* __restrict__ v3,
    const float* __restrict__ g4, const float* __restrict__ b4, const float* __restrict__ m4, const float* __restrict__ v4,
    const float* __restrict__ g5, const float* __restrict__ b5, const float* __restrict__ m5, const float* __restrict__ v5,
    const float* __restrict__ g6, const float* __restrict__ b6, const float* __restrict__ m6, const float* __restrict__ v6,
    float* __restrict__ P, _Float16* __restrict__ Wh, _Float16* __restrict__ z) {
  const int bid = blockIdx.x, tid = threadIdx.x;
  if (bid < 512) {
    const int o  = tid & 63;
    const int pi = tid >> 6;
    const float ww0 = w1[o * 3 + 0], ww1 = w1[o * 3 + 1], ww2 = w1[o * 3 + 2];
    const float iv = g1[o] * rsqrtf(v1[o] + EPS);
    const int pbase = bid * 64;
    const int b = pbase >> 12;
    const int nbase = pbase & (N_ - 1);
    const float* xb = x + (size_t)b * 3 * N_;
    for (int pj = pi; pj < 64; pj += 4) {
      const int n = nbase + pj;
      const float x0 = xb[n], x1v = xb[N_ + n], x2v = xb[2 * N_ + n];
      z[(size_t)(pbase + pj) * 64 + o] = (_Float16)((x0 * ww0 + x1v * ww1 + x2v * ww2) * iv);
    }
    return;
  }
  if (bid == 1328) {
    const float* G[6]  = {g1, g2, g3, g4, g5, g6};
    const float* Bb[6] = {b1, b2, b3, b4, b5, b6};
    const float* Mm[6] = {m1, m2, m3, m4, m5, m6};
    const float* Vv[6] = {v1, v2, v3, v4, v5, v6};
    const int Cs[6] = {64, 64, 128, 256, 256, 128};
    const int OI[6] = {0, 128, 256, 512, 1024, 1536};
    const int OB[6] = {64, 192, 384, 768, 1280, 1664};
    for (int l = 0; l < 6; ++l) {
      for (int c = tid; c < Cs[l]; c += 256) {
        float iv = G[l][c] * rsqrtf(Vv[l][c] + EPS);
        P[OI[l] + c] = iv;
        P[OB[l] + c] = Bb[l][c] - Mm[l][c] * iv;
      }
    }
    return;
  }
  const int fb = bid - 512;
  const float* w; const float* g; const float* v; _Float16* dst; int lc, base;
  if (fb < 16)       { w = w2; g = g2; v = v2; dst = Wh + 0;      lc = 6; base = 0;   }
  else if (fb < 48)  { w = w3; g = g3; v = v3; dst = Wh + 4096;   lc = 6; base = 16;  }
  else if (fb < 176) { w = w4; g = g4; v = v4; dst = Wh + 12288;  lc = 7; base = 48;  }
  else if (fb < 688) { w = w5; g = g5; v = v5; dst = Wh + 45056;  lc = 9; base = 176; }
  else               { w = w6; g = g6; v = v6; dst = Wh + 176128; lc = 8; base = 688; }
  const int e = (fb - base) * 256 + tid;
  const int o = e >> lc;
  dst[e] = (_Float16)(w[e] * (g[o] * rsqrtf(v[o] + EPS)));
}

// ---------------- fused edge(C=64) + small GEMM ------------------------------
template <int BO>
__global__ __launch_bounds__(256) void edge_gemm64(
    const _Float16* __restrict__ z, const int* __restrict__ idx,
    const float* __restrict__ betap,
    const _Float16* __restrict__ W,           // (BO, 64) inv-folded
    _Float16* __restrict__ hout,              // h512 column base (ld 512)
    _Float16* __restrict__ zout, int ldzout) {
  constexpr int GW = BO / 8;
  constexpr int OJ = BO / 32;
  __shared__ _Float16 Asmem[128 * 64];
  __shared__ _Float16 Wsmem[BO * 64];

  const int tid = threadIdx.x, lane = tid & 63, wid = tid >> 6;
  const int batch = blockIdx.x & 7, chunk = blockIdx.x >> 3;
  const int bm0 = (batch << 12) + chunk * 128;
  const int lr = lane & 15, lk = lane >> 4;

  const _Float16* Wbase = W + (size_t)lr * 64 + lk * 8;
#pragma unroll
  for (int g = wid; g < GW; g += 4) {
    const int o = g >> 1, s = g & 1;
    gload_lds16(Wbase + (size_t)16 * o * 64 + s * 32, Wsmem + g * 512);
  }

  const int lid = tid & 7, cb = lid * 8;
  float bt[8];
#pragma unroll
  for (int q = 0; q < 8; ++q) bt[q] = betap[cb + q];
  const _Float16* zb = z + ((size_t)(batch << 12)) * 64;
#pragma unroll
  for (int pass = 0; pass < 4; ++pass) {
    const int pi = pass * 32 + (tid >> 3);
    const int p = bm0 + pi;
    const int* ip = idx + (size_t)p * K_;
    const int ir0 = ip[lid];
    const int ir1 = ip[8 + lid];
    const int ir2 = ip[16 + (lid & 3)];
    f16x8 mx = *reinterpret_cast<const f16x8*>(zb + (size_t)__shfl(ir0, 0, 8) * 64 + cb);
#pragma unroll
    for (int k = 1; k < K_; ++k) {
      const int g = (k < 8) ? __shfl(ir0, k, 8)
                  : (k < 16) ? __shfl(ir1, k - 8, 8)
                             : __shfl(ir2, k - 16, 8);
      const f16x8 v = *reinterpret_cast<const f16x8*>(zb + (size_t)g * 64 + cb);
#pragma unroll
      for (int q = 0; q < 8; ++q) mx[q] = v[q] > mx[q] ? v[q] : mx[q];
    }
    const f16x8 vc = *reinterpret_cast<const f16x8*>(z + (size_t)p * 64 + cb);
    f16x8 vo;
#pragma unroll
    for (int q = 0; q < 8; ++q) {
      const float e = (float)mx[q] - (float)vc[q] + bt[q];
      vo[q] = (_Float16)fmaxf(e, NEG * e);
    }
    *reinterpret_cast<f16x8*>(hout + (size_t)p * 512 + cb) = vo;
    const int i = pi >> 4, rr = pi & 15, s = cb >> 5, kk = (cb >> 3) & 3;
    *reinterpret_cast<f16x8*>(Asmem + (i * 2 + s) * 512 + ((kk << 4) | rr) * 8) = vo;
  }
  __syncthreads();

  const int wr = wid >> 1, wc = wid & 1;
  f32x4 acc[4][OJ];
#pragma unroll
  for (int i = 0; i < 4; ++i)
#pragma unroll
    for (int j = 0; j < OJ; ++j) acc[i][j] = (f32x4){0.f, 0.f, 0.f, 0.f};
#pragma unroll
  for (int s = 0; s < 2; ++s) {
    f16x8 av[4], wv[OJ];
#pragma unroll
    for (int i = 0; i < 4; ++i)
      av[i] = *reinterpret_cast<const f16x8*>(Asmem + ((wr * 4 + i) * 2 + s) * 512 + lane * 8);
#pragma unroll
    for (int j = 0; j < OJ; ++j)
      wv[j] = *reinterpret_cast<const f16x8*>(Wsmem + ((wc * OJ + j) * 2 + s) * 512 + lane * 8);
#pragma unroll
    for (int i = 0; i < 4; ++i)
#pragma unroll
      for (int j = 0; j < OJ; ++j)
        acc[i][j] = __builtin_amdgcn_mfma_f32_16x16x32_f16(av[i], wv[j], acc[i][j], 0, 0, 0);
  }

#pragma unroll
  for (int j = 0; j < OJ; ++j) {
    const int o = wc * (BO / 2) + 16 * j + lr;
#pragma unroll
    for (int i = 0; i < 4; ++i) {
      const int r0 = bm0 + wr * 64 + 16 * i + lk * 4;
#pragma unroll
      for (int q = 0; q < 4; ++q)
        zout[(size_t)(r0 + q) * ldzout + o] = (_Float16)acc[i][j][q];
    }
  }
}

// ---------------- fp16 MFMA GEMM, 4-buffer counted-vmcnt pipeline ------------
// MODE 0: out=acc  MODE 1: lrelu(acc+beta)  MODE 2: MODE1 then fused dot w7
// blockIdx.x is batch-XCD swizzled: batch = bid&7 -> A rows L2-resident/XCD.
template <int BM, int BO, int C, int MODE>
__global__ __launch_bounds__(256, 2) void gemm_pipe(
    const _Float16* __restrict__ A, int lda,
    const _Float16* __restrict__ W,
    const float* __restrict__ betap,
    _Float16* __restrict__ out, int ldout,
    const float* __restrict__ w7, float* __restrict__ dout) {
  constexpr int NK = C / 32;
  constexpr int GA = BM / 16;
  constexpr int GW = BO / 16;
  constexpr int GT = GA + GW;
  constexpr int GP = GT / 4;
  constexpr int SB = (BM + BO) * 32;
  constexpr int MI = BM / 32, OJ = BO / 32;
  __shared__ _Float16 lds[4 * SB];

  const int lane = threadIdx.x & 63;
  const int wid  = threadIdx.x >> 6;
  const int wr = wid >> 1, wc = wid & 1;
  const int bid = blockIdx.x;
  const int bm0 = ((bid & 7) << 12) + (bid >> 3) * BM;   // batch-XCD swizzle
  const int bo0 = blockIdx.y * BO;
  const int lr = lane & 15, lk = lane >> 4;

  const _Float16* Abase = A + (size_t)(bm0 + lr) * lda + lk * 8;
  const _Float16* Wbase = W + (size_t)(bo0 + lr) * C + lk * 8;

  f32x4 acc[MI][OJ];
#pragma unroll
  for (int i = 0; i < MI; ++i)
#pragma unroll
    for (int j = 0; j < OJ; ++j) acc[i][j] = (f32x4){0.f, 0.f, 0.f, 0.f};

  auto stage = [&](int buf, int k0) {
    _Float16* dst = &lds[buf * SB];
#pragma unroll
    for (int q = 0; q < GP; ++q) {
      const int g = wid * GP + q;
      const _Float16* src = (g < GA)
          ? Abase + (size_t)16 * g * lda + k0
          : Wbase + (size_t)16 * (g - GA) * C + k0;
      gload_lds16(src, dst + g * 512);
    }
  };

  auto compute = [&](int buf) {
    const _Float16* Ab = &lds[buf * SB];
    const _Float16* Wb = &lds[buf * SB + GA * 512];
    f16x8 av[MI], wv[OJ];
#pragma unroll
    for (int i = 0; i < MI; ++i)
      av[i] = *reinterpret_cast<const f16x8*>(Ab + (wr * MI + i) * 512 + lane * 8);
#pragma unroll
    for (int j = 0; j < OJ; ++j)
      wv[j] = *reinterpret_cast<const f16x8*>(Wb + (wc * OJ + j) * 512 + lane * 8);
#pragma unroll
    for (int i = 0; i < MI; ++i)
#pragma unroll
      for (int j = 0; j < OJ; ++j)
        acc[i][j] = __builtin_amdgcn_mfma_f32_16x16x32_f16(av[i], wv[j], acc[i][j], 0, 0, 0);
  };

  stage(0, 0);
  stage(1, 32);
#pragma unroll
  for (int t = 0; t < NK; ++t) {
    if (t + 2 < NK) {
      stage((t + 2) & 3, (t + 2) * 32);
      if constexpr (GP == 3)      asm volatile("s_waitcnt vmcnt(6)" ::: "memory");
      else if constexpr (GP == 4) asm volatile("s_waitcnt vmcnt(8)" ::: "memory");
      else                        asm volatile("s_waitcnt vmcnt(12)" ::: "memory");
    } else if (t + 1 < NK) {
      if constexpr (GP == 3)      asm volatile("s_waitcnt vmcnt(3)" ::: "memory");
      else if constexpr (GP == 4) asm volatile("s_waitcnt vmcnt(4)" ::: "memory");
      else                        asm volatile("s_waitcnt vmcnt(6)" ::: "memory");
    } else {
      asm volatile("s_waitcnt vmcnt(0)" ::: "memory");
    }
    __builtin_amdgcn_s_barrier();
    compute(t & 3);
  }

  if constexpr (MODE == 2) {
    __shared__ float dotbuf[BM][2];
    float rowdot[MI][4];
#pragma unroll
    for (int i = 0; i < MI; ++i)
#pragma unroll
      for (int q = 0; q < 4; ++q) rowdot[i][q] = 0.f;
#pragma unroll
    for (int j = 0; j < OJ; ++j) {
      const int o = wc * (BO / 2) + 16 * j + lr;
      const float bt = betap[o];
      const float wf = w7[o];
#pragma unroll
      for (int i = 0; i < MI; ++i)
#pragma unroll
        for (int q = 0; q < 4; ++q) {
          float t = acc[i][j][q] + bt;
          t = fmaxf(t, NEG * t);
          rowdot[i][q] += t * wf;
        }
    }
#pragma unroll
    for (int i = 0; i < MI; ++i)
#pragma unroll
      for (int q = 0; q < 4; ++q) {
#pragma unroll
        for (int off = 1; off < 16; off <<= 1)
          rowdot[i][q] += __shfl_xor(rowdot[i][q], off, 16);
        if (lr == 0) dotbuf[wr * (BM / 2) + 16 * i + lk * 4 + q][wc] = rowdot[i][q];
      }
    __syncthreads();
    if (threadIdx.x < BM) {
      const float s = dotbuf[threadIdx.x][0] + dotbuf[threadIdx.x][1];
      dout[bm0 + threadIdx.x] = fmaxf(s, NEG * s);
    }
    return;
  }

#pragma unroll
  for (int j = 0; j < OJ; ++j) {
    const int o = bo0 + wc * (BO / 2) + 16 * j + lr;
    const float bt = (MODE == 1) ? betap[o] : 0.f;
#pragma unroll
    for (int i = 0; i < MI; ++i) {
      const int r0 = bm0 + wr * (BM / 2) + 16 * i + lk * 4;
#pragma unroll
      for (int q = 0; q < 4; ++q) {
        float t = acc[i][j][q];
        if (MODE == 1) { t += bt; t = fmaxf(t, NEG * t); }
        out[(size_t)(r0 + q) * ldout + o] = (_Float16)t;
      }
    }
  }
}

// ---------------- edge max, standalone (O=128/256) ---------------------------
template <int O>
__global__ __launch_bounds__(256) void edge_max8(
    const _Float16* __restrict__ z, const int* __restrict__ idx,
    const float* __restrict__ betap, _Float16* __restrict__ out, int ldout) {
  constexpr int TPP = O / 8;
  constexpr int PPB = 256 / TPP;
  constexpr int NW = (K_ + TPP - 1) / TPP;
  const int t = threadIdx.x;
  const int batch = blockIdx.x & 7;
  const int chunk = blockIdx.x >> 3;
  const int p = (batch << 12) + chunk * PPB + t / TPP;
  const int lid = t % TPP;
  const int cb = lid * 8;
  const int* ip = idx + (size_t)p * K_;
  int ir[NW];
#pragma unroll
  for (int wv = 0; wv < NW; ++wv) {
    const int l = wv * TPP + lid;
    ir[wv] = (l < K_) ? ip[l] : ip[0];
  }
  const _Float16* zb = z + ((size_t)(batch << 12)) * O;

  f16x8 mx = *reinterpret_cast<const f16x8*>(zb + (size_t)__shfl(ir[0], 0, TPP) * O + cb);
#pragma unroll
  for (int k = 1; k < K_; ++k) {
    const int g = __shfl(ir[k / TPP], k % TPP, TPP);
    const f16x8 v = *reinterpret_cast<const f16x8*>(zb + (size_t)g * O + cb);
#pragma unroll
    for (int q = 0; q < 8; ++q) mx[q] = v[q] > mx[q] ? v[q] : mx[q];
  }
  const f16x8 vc = *reinterpret_cast<const f16x8*>(z + (size_t)p * O + cb);
  f16x8 vo;
#pragma unroll
  for (int q = 0; q < 8; ++q) {
    const float e = (float)mx[q] - (float)vc[q] + betap[cb + q];
    vo[q] = (_Float16)fmaxf(e, NEG * e);
  }
  *reinterpret_cast<f16x8*>(out + (size_t)p * ldout + cb) = vo;
}

// ---------------- launch -----------------------------------------------------
extern "C" void kernel_launch(void* const* d_in, const int* in_sizes, int n_in,
                              void* d_out, int out_size, void* d_ws, size_t ws_size,
                              hipStream_t stream) {
  const float* x  = (const float*)d_in[0];
  const int* idx  = (const int*)d_in[1];
  const float* w[7];
  for (int i = 0; i < 7; ++i) w[i] = (const float*)d_in[2 + i];
  const float* bn[24];
  for (int i = 0; i < 24; ++i) bn[i] = (const float*)d_in[9 + i];

  // ws: P@0 (32KB) | Wh@32KB (~0.42MB) | z_a@1MB (16MB) | h512@17MB (32MB) | z_b@49MB (16MB)
  float* P       = (float*)d_ws;
  _Float16* Wh   = (_Float16*)((char*)d_ws + (32 << 10));
  _Float16* z_a  = (_Float16*)((char*)d_ws + (1u << 20));
  _Float16* h512 = (_Float16*)((char*)d_ws + (17u << 20));
  _Float16* z_b  = (_Float16*)((char*)d_ws + (49u << 20));

  prep_c3<<<1329, 256, 0, stream>>>(
      x, w[0], w[1], w[2], w[3], w[4], w[5],
      bn[0], bn[1], bn[2], bn[3],   bn[4], bn[5], bn[6], bn[7],
      bn[8], bn[9], bn[10], bn[11], bn[12], bn[13], bn[14], bn[15],
      bn[16], bn[17], bn[18], bn[19], bn[20], bn[21], bn[22], bn[23],
      P, Wh, z_a);

  const float* bt1 = P + 64;
  const float* bt2 = P + 192;
  const float* bt3 = P + 384;
  const float* bt4 = P + 768;
  const float* bt5 = P + 1280;
  const float* bt6 = P + 1664;
  const _Float16* W2 = Wh + 0, *W3 = Wh + 4096, *W4 = Wh + 12288,
               *W5 = Wh + 45056, *W6 = Wh + 176128;

  // L1 edge + L2 GEMM fused: z1 -> (x1 -> h512+0, z2 -> z_b ld 64)
  edge_gemm64<64><<<M_ / 128, 256, 0, stream>>>(z_a, idx, bt1, W2, h512 + 0, z_b, 64);
  // L2 edge + L3 GEMM fused: z2 -> (x2 -> h512+64, z3 -> z_a ld 128)
  edge_gemm64<128><<<M_ / 128, 256, 0, stream>>>(z_b, idx, bt2, W3, h512 + 64, z_a, 128);
  // L3 edge: z3 -> x3 (h512+128)
  edge_max8<128><<<M_ / 16, 256, 0, stream>>>(z_a, idx, bt3, h512 + 128, 512);
  // L4 GEMM: x3 -> z4 (z_b ld 256)
  gemm_pipe<128, 128, 128, 0><<<dim3(M_ / 128, 2), 256, 0, stream>>>(
      h512 + 128, 512, W4, nullptr, z_b, 256, nullptr, nullptr);
  // L4 edge: z4 -> x4 (h512+256)
  edge_max8<256><<<M_ / 8, 256, 0, stream>>>(z_b, idx, bt4, h512 + 256, 512);
  // L5: pointconv(512 -> 256) -> z_a ld 256
  gemm_pipe<128, 128, 512, 1><<<dim3(M_ / 128, 2), 256, 0, stream>>>(
      h512, 512, W5, bt5, z_a, 256, nullptr, nullptr);
  // L6+L7: pointconv(256 -> 128) fused with final 128 -> 1 + lrelu
  gemm_pipe<64, 128, 256, 2><<<dim3(M_ / 64, 1), 256, 0, stream>>>(
      z_a, 256, W6, bt6, nullptr, 0, w[6], (float*)d_out);
}

// Round 10
// 103.965 us; speedup vs baseline: 1.0447x; 1.0351x over previous
//
#include <hip/hip_runtime.h>
#include <hip/hip_bf16.h>
#include <cstdint>
#include <cstddef>

#define EPS 1e-5f
#define NEG 0.2f

static constexpr int B_ = 8, N_ = 4096, K_ = 20, M_ = B_ * N_;  // M = 32768

typedef __attribute__((ext_vector_type(8))) _Float16 f16x8;
typedef __attribute__((ext_vector_type(4))) float f32x4;

// async global->LDS, 16B per lane; LDS dest = wave-uniform base + lane*16
__device__ __forceinline__ void gload_lds16(const _Float16* g, _Float16* l) {
  __builtin_amdgcn_global_load_lds(
      (const __attribute__((address_space(1))) uint32_t*)g,
      (__attribute__((address_space(3))) uint32_t*)l, 16, 0, 0);
}

// ---------------- prep + layer-1 C=3 GEMM, one kernel ------------------------
// blocks 0..511: gemm_c3 ; 512..1327: weight fold ; 1328: BN param table
__global__ __launch_bounds__(256) void prep_c3(
    const float* __restrict__ x, const float* __restrict__ w1,
    const float* __restrict__ w2, const float* __restrict__ w3,
    const float* __restrict__ w4, const float* __restrict__ w5,
    const float* __restrict__ w6,
    const float* __restrict__ g1, const float* __restrict__ b1, const float* __restrict__ m1, const float* __restrict__ v1,
    const float* __restrict__ g2, const float* __restrict__ b2, const float* __restrict__ m2, const float* __restrict__ v2,
    const float* __restrict__ g3, const float* __restrict__ b3, const float* __restrict__ m3, const float* __restrict__ v3,
    const float* __restrict__ g4, const float* __restrict__ b4, const float* __restrict__ m4, const float* __restrict__ v4,
    const float* __restrict__ g5, const float* __restrict__ b5, const float* __restrict__ m5, const float* __restrict__ v5,
    const float* __restrict__ g6, const float* __restrict__ b6, const float* __restrict__ m6, const float* __restrict__ v6,
    float* __restrict__ P, _Float16* __restrict__ Wh, _Float16* __restrict__ z) {
  const int bid = blockIdx.x, tid = threadIdx.x;
  if (bid < 512) {
    const int o  = tid & 63;
    const int pi = tid >> 6;
    const float ww0 = w1[o * 3 + 0], ww1 = w1[o * 3 + 1], ww2 = w1[o * 3 + 2];
    const float iv = g1[o] * rsqrtf(v1[o] + EPS);
    const int pbase = bid * 64;
    const int b = pbase >> 12;
    const int nbase = pbase & (N_ - 1);
    const float* xb = x + (size_t)b * 3 * N_;
    for (int pj = pi; pj < 64; pj += 4) {
      const int n = nbase + pj;
      const float x0 = xb[n], x1v = xb[N_ + n], x2v = xb[2 * N_ + n];
      z[(size_t)(pbase + pj) * 64 + o] = (_Float16)((x0 * ww0 + x1v * ww1 + x2v * ww2) * iv);
    }
    return;
  }
  if (bid == 1328) {
    const float* G[6]  = {g1, g2, g3, g4, g5, g6};
    const float* Bb[6] = {b1, b2, b3, b4, b5, b6};
    const float* Mm[6] = {m1, m2, m3, m4, m5, m6};
    const float* Vv[6] = {v1, v2, v3, v4, v5, v6};
    const int Cs[6] = {64, 64, 128, 256, 256, 128};
    const int OI[6] = {0, 128, 256, 512, 1024, 1536};
    const int OB[6] = {64, 192, 384, 768, 1280, 1664};
    for (int l = 0; l < 6; ++l) {
      for (int c = tid; c < Cs[l]; c += 256) {
        float iv = G[l][c] * rsqrtf(Vv[l][c] + EPS);
        P[OI[l] + c] = iv;
        P[OB[l] + c] = Bb[l][c] - Mm[l][c] * iv;
      }
    }
    return;
  }
  const int fb = bid - 512;
  const float* w; const float* g; const float* v; _Float16* dst; int lc, base;
  if (fb < 16)       { w = w2; g = g2; v = v2; dst = Wh + 0;      lc = 6; base = 0;   }
  else if (fb < 48)  { w = w3; g = g3; v = v3; dst = Wh + 4096;   lc = 6; base = 16;  }
  else if (fb < 176) { w = w4; g = g4; v = v4; dst = Wh + 12288;  lc = 7; base = 48;  }
  else if (fb < 688) { w = w5; g = g5; v = v5; dst = Wh + 45056;  lc = 9; base = 176; }
  else               { w = w6; g = g6; v = v6; dst = Wh + 176128; lc = 8; base = 688; }
  const int e = (fb - base) * 256 + tid;
  const int o = e >> lc;
  dst[e] = (_Float16)(w[e] * (g[o] * rsqrtf(v[o] + EPS)));
}

// ---------------- fused edge(C=64) + small GEMM ------------------------------
template <int BO>
__global__ __launch_bounds__(256) void edge_gemm64(
    const _Float16* __restrict__ z, const int* __restrict__ idx,
    const float* __restrict__ betap,
    const _Float16* __restrict__ W,           // (BO, 64) inv-folded
    _Float16* __restrict__ hout,              // h512 column base (ld 512)
    _Float16* __restrict__ zout, int ldzout) {
  constexpr int GW = BO / 8;
  constexpr int OJ = BO / 32;
  __shared__ _Float16 Asmem[128 * 64];
  __shared__ _Float16 Wsmem[BO * 64];

  const int tid = threadIdx.x, lane = tid & 63, wid = tid >> 6;
  const int batch = blockIdx.x & 7, chunk = blockIdx.x >> 3;
  const int bm0 = (batch << 12) + chunk * 128;
  const int lr = lane & 15, lk = lane >> 4;

  const _Float16* Wbase = W + (size_t)lr * 64 + lk * 8;
#pragma unroll
  for (int g = wid; g < GW; g += 4) {
    const int o = g >> 1, s = g & 1;
    gload_lds16(Wbase + (size_t)16 * o * 64 + s * 32, Wsmem + g * 512);
  }

  const int lid = tid & 7, cb = lid * 8;
  float bt[8];
#pragma unroll
  for (int q = 0; q < 8; ++q) bt[q] = betap[cb + q];
  const _Float16* zb = z + ((size_t)(batch << 12)) * 64;
#pragma unroll
  for (int pass = 0; pass < 4; ++pass) {
    const int pi = pass * 32 + (tid >> 3);
    const int p = bm0 + pi;
    const int* ip = idx + (size_t)p * K_;
    const int ir0 = ip[lid];
    const int ir1 = ip[8 + lid];
    const int ir2 = ip[16 + (lid & 3)];
    f16x8 mx = *reinterpret_cast<const f16x8*>(zb + (size_t)__shfl(ir0, 0, 8) * 64 + cb);
#pragma unroll
    for (int k = 1; k < K_; ++k) {
      const int g = (k < 8) ? __shfl(ir0, k, 8)
                  : (k < 16) ? __shfl(ir1, k - 8, 8)
                             : __shfl(ir2, k - 16, 8);
      const f16x8 v = *reinterpret_cast<const f16x8*>(zb + (size_t)g * 64 + cb);
#pragma unroll
      for (int q = 0; q < 8; ++q) mx[q] = v[q] > mx[q] ? v[q] : mx[q];
    }
    const f16x8 vc = *reinterpret_cast<const f16x8*>(z + (size_t)p * 64 + cb);
    f16x8 vo;
#pragma unroll
    for (int q = 0; q < 8; ++q) {
      const float e = (float)mx[q] - (float)vc[q] + bt[q];
      vo[q] = (_Float16)fmaxf(e, NEG * e);
    }
    *reinterpret_cast<f16x8*>(hout + (size_t)p * 512 + cb) = vo;
    const int i = pi >> 4, rr = pi & 15, s = cb >> 5, kk = (cb >> 3) & 3;
    *reinterpret_cast<f16x8*>(Asmem + (i * 2 + s) * 512 + ((kk << 4) | rr) * 8) = vo;
  }
  __syncthreads();

  const int wr = wid >> 1, wc = wid & 1;
  f32x4 acc[4][OJ];
#pragma unroll
  for (int i = 0; i < 4; ++i)
#pragma unroll
    for (int j = 0; j < OJ; ++j) acc[i][j] = (f32x4){0.f, 0.f, 0.f, 0.f};
#pragma unroll
  for (int s = 0; s < 2; ++s) {
    f16x8 av[4], wv[OJ];
#pragma unroll
    for (int i = 0; i < 4; ++i)
      av[i] = *reinterpret_cast<const f16x8*>(Asmem + ((wr * 4 + i) * 2 + s) * 512 + lane * 8);
#pragma unroll
    for (int j = 0; j < OJ; ++j)
      wv[j] = *reinterpret_cast<const f16x8*>(Wsmem + ((wc * OJ + j) * 2 + s) * 512 + lane * 8);
#pragma unroll
    for (int i = 0; i < 4; ++i)
#pragma unroll
      for (int j = 0; j < OJ; ++j)
        acc[i][j] = __builtin_amdgcn_mfma_f32_16x16x32_f16(av[i], wv[j], acc[i][j], 0, 0, 0);
  }

#pragma unroll
  for (int j = 0; j < OJ; ++j) {
    const int o = wc * (BO / 2) + 16 * j + lr;
#pragma unroll
    for (int i = 0; i < 4; ++i) {
      const int r0 = bm0 + wr * 64 + 16 * i + lk * 4;
#pragma unroll
      for (int q = 0; q < 4; ++q)
        zout[(size_t)(r0 + q) * ldzout + o] = (_Float16)acc[i][j][q];
    }
  }
}

// ---------------- fp16 MFMA GEMM, 4-wave, 4-buffer counted-vmcnt pipeline ----
template <int BM, int BO, int C, int MODE>
__global__ __launch_bounds__(256, 2) void gemm_pipe(
    const _Float16* __restrict__ A, int lda,
    const _Float16* __restrict__ W,
    const float* __restrict__ betap,
    _Float16* __restrict__ out, int ldout) {
  constexpr int NK = C / 32;
  constexpr int GA = BM / 16;
  constexpr int GW = BO / 16;
  constexpr int GT = GA + GW;
  constexpr int GP = GT / 4;
  constexpr int SB = (BM + BO) * 32;
  constexpr int MI = BM / 32, OJ = BO / 32;
  __shared__ _Float16 lds[4 * SB];

  const int lane = threadIdx.x & 63;
  const int wid  = threadIdx.x >> 6;
  const int wr = wid >> 1, wc = wid & 1;
  const int bid = blockIdx.x;
  const int bm0 = ((bid & 7) << 12) + (bid >> 3) * BM;   // batch-XCD swizzle
  const int bo0 = blockIdx.y * BO;
  const int lr = lane & 15, lk = lane >> 4;

  const _Float16* Abase = A + (size_t)(bm0 + lr) * lda + lk * 8;
  const _Float16* Wbase = W + (size_t)(bo0 + lr) * C + lk * 8;

  f32x4 acc[MI][OJ];
#pragma unroll
  for (int i = 0; i < MI; ++i)
#pragma unroll
    for (int j = 0; j < OJ; ++j) acc[i][j] = (f32x4){0.f, 0.f, 0.f, 0.f};

  auto stage = [&](int buf, int k0) {
    _Float16* dst = &lds[buf * SB];
#pragma unroll
    for (int q = 0; q < GP; ++q) {
      const int g = wid * GP + q;
      const _Float16* src = (g < GA)
          ? Abase + (size_t)16 * g * lda + k0
          : Wbase + (size_t)16 * (g - GA) * C + k0;
      gload_lds16(src, dst + g * 512);
    }
  };

  auto compute = [&](int buf) {
    const _Float16* Ab = &lds[buf * SB];
    const _Float16* Wb = &lds[buf * SB + GA * 512];
    f16x8 av[MI], wv[OJ];
#pragma unroll
    for (int i = 0; i < MI; ++i)
      av[i] = *reinterpret_cast<const f16x8*>(Ab + (wr * MI + i) * 512 + lane * 8);
#pragma unroll
    for (int j = 0; j < OJ; ++j)
      wv[j] = *reinterpret_cast<const f16x8*>(Wb + (wc * OJ + j) * 512 + lane * 8);
#pragma unroll
    for (int i = 0; i < MI; ++i)
#pragma unroll
      for (int j = 0; j < OJ; ++j)
        acc[i][j] = __builtin_amdgcn_mfma_f32_16x16x32_f16(av[i], wv[j], acc[i][j], 0, 0, 0);
  };

  stage(0, 0);
  stage(1, 32);
#pragma unroll
  for (int t = 0; t < NK; ++t) {
    if (t + 2 < NK) {
      stage((t + 2) & 3, (t + 2) * 32);
      if constexpr (GP == 3)      asm volatile("s_waitcnt vmcnt(6)" ::: "memory");
      else                        asm volatile("s_waitcnt vmcnt(8)" ::: "memory");
    } else if (t + 1 < NK) {
      if constexpr (GP == 3)      asm volatile("s_waitcnt vmcnt(3)" ::: "memory");
      else                        asm volatile("s_waitcnt vmcnt(4)" ::: "memory");
    } else {
      asm volatile("s_waitcnt vmcnt(0)" ::: "memory");
    }
    __builtin_amdgcn_s_barrier();
    compute(t & 3);
  }

#pragma unroll
  for (int j = 0; j < OJ; ++j) {
    const int o = bo0 + wc * (BO / 2) + 16 * j + lr;
    const float bt = (MODE == 1) ? betap[o] : 0.f;
#pragma unroll
    for (int i = 0; i < MI; ++i) {
      const int r0 = bm0 + wr * (BM / 2) + 16 * i + lk * 4;
#pragma unroll
      for (int q = 0; q < 4; ++q) {
        float t = acc[i][j][q];
        if (MODE == 1) { t += bt; t = fmaxf(t, NEG * t); }
        out[(size_t)(r0 + q) * ldout + o] = (_Float16)t;
      }
    }
  }
}

// ---------------- fp16 MFMA GEMM, 8-wave (512 thr), ring-4 pipeline ----------
// Wave grid 2x4 (wr row-half, wc col-quarter). Single-y: W read once, A once.
// MODE 1: lrelu(acc+beta) -> out   MODE 2: MODE1 then fused 128->1 dot w7
template <int BM, int BO, int C, int MODE>
__global__ __launch_bounds__(512, 1) void gemm_pipe8(
    const _Float16* __restrict__ A, int lda,
    const _Float16* __restrict__ W,
    const float* __restrict__ betap,
    _Float16* __restrict__ out, int ldout,
    const float* __restrict__ w7, float* __restrict__ dout) {
  constexpr int NK = C / 32;
  constexpr int GA = BM / 16;
  constexpr int GW = BO / 16;
  constexpr int GT = GA + GW;
  constexpr int GP = GT / 8;             // groups per wave
  constexpr int SB = (BM + BO) * 32;
  constexpr int MI = BM / 32;            // per-wave row frags (wr in {0,1})
  constexpr int OJ = BO / 64;            // per-wave col frags (wc in {0..3})
  __shared__ _Float16 lds[4 * SB];

  const int lane = threadIdx.x & 63;
  const int wid  = threadIdx.x >> 6;     // 0..7
  const int wr = wid >> 2, wc = wid & 3;
  const int bid = blockIdx.x;
  const int bm0 = ((bid & 7) << 12) + (bid >> 3) * BM;   // batch-XCD swizzle
  const int lr = lane & 15, lk = lane >> 4;

  const _Float16* Abase = A + (size_t)(bm0 + lr) * lda + lk * 8;
  const _Float16* Wbase = W + (size_t)lr * C + lk * 8;

  f32x4 acc[MI][OJ];
#pragma unroll
  for (int i = 0; i < MI; ++i)
#pragma unroll
    for (int j = 0; j < OJ; ++j) acc[i][j] = (f32x4){0.f, 0.f, 0.f, 0.f};

  auto stage = [&](int buf, int k0) {
    _Float16* dst = &lds[buf * SB];
#pragma unroll
    for (int q = 0; q < GP; ++q) {
      const int g = wid * GP + q;
      const _Float16* src = (g < GA)
          ? Abase + (size_t)16 * g * lda + k0
          : Wbase + (size_t)16 * (g - GA) * C + k0;
      gload_lds16(src, dst + g * 512);
    }
  };

  auto compute = [&](int buf) {
    const _Float16* Ab = &lds[buf * SB];
    const _Float16* Wb = &lds[buf * SB + GA * 512];
    f16x8 av[MI], wv[OJ];
#pragma unroll
    for (int i = 0; i < MI; ++i)
      av[i] = *reinterpret_cast<const f16x8*>(Ab + (wr * MI + i) * 512 + lane * 8);
#pragma unroll
    for (int j = 0; j < OJ; ++j)
      wv[j] = *reinterpret_cast<const f16x8*>(Wb + (wc * OJ + j) * 512 + lane * 8);
#pragma unroll
    for (int i = 0; i < MI; ++i)
#pragma unroll
      for (int j = 0; j < OJ; ++j)
        acc[i][j] = __builtin_amdgcn_mfma_f32_16x16x32_f16(av[i], wv[j], acc[i][j], 0, 0, 0);
  };

  stage(0, 0);
  stage(1, 32);
#pragma unroll
  for (int t = 0; t < NK; ++t) {
    if (t + 2 < NK) {
      stage((t + 2) & 3, (t + 2) * 32);
      if constexpr (GP == 2)      asm volatile("s_waitcnt vmcnt(4)" ::: "memory");
      else                        asm volatile("s_waitcnt vmcnt(6)" ::: "memory");
    } else if (t + 1 < NK) {
      if constexpr (GP == 2)      asm volatile("s_waitcnt vmcnt(2)" ::: "memory");
      else                        asm volatile("s_waitcnt vmcnt(3)" ::: "memory");
    } else {
      asm volatile("s_waitcnt vmcnt(0)" ::: "memory");
    }
    __builtin_amdgcn_s_barrier();
    compute(t & 3);
  }

  if constexpr (MODE == 2) {
    __shared__ float dotbuf[BM][4];
    float rowdot[MI][4];
#pragma unroll
    for (int i = 0; i < MI; ++i)
#pragma unroll
      for (int q = 0; q < 4; ++q) rowdot[i][q] = 0.f;
#pragma unroll
    for (int j = 0; j < OJ; ++j) {
      const int o = wc * (BO / 4) + 16 * j + lr;
      const float bt = betap[o];
      const float wf = w7[o];
#pragma unroll
      for (int i = 0; i < MI; ++i)
#pragma unroll
        for (int q = 0; q < 4; ++q) {
          float t = acc[i][j][q] + bt;
          t = fmaxf(t, NEG * t);
          rowdot[i][q] += t * wf;
        }
    }
#pragma unroll
    for (int i = 0; i < MI; ++i)
#pragma unroll
      for (int q = 0; q < 4; ++q) {
#pragma unroll
        for (int off = 1; off < 16; off <<= 1)
          rowdot[i][q] += __shfl_xor(rowdot[i][q], off, 16);
        if (lr == 0) dotbuf[wr * (BM / 2) + 16 * i + lk * 4 + q][wc] = rowdot[i][q];
      }
    __syncthreads();
    if (threadIdx.x < BM) {
      const float s = dotbuf[threadIdx.x][0] + dotbuf[threadIdx.x][1] +
                      dotbuf[threadIdx.x][2] + dotbuf[threadIdx.x][3];
      dout[bm0 + threadIdx.x] = fmaxf(s, NEG * s);
    }
    return;
  }

#pragma unroll
  for (int j = 0; j < OJ; ++j) {
    const int o = wc * (BO / 4) + 16 * j + lr;
    const float bt = betap[o];
#pragma unroll
    for (int i = 0; i < MI; ++i) {
      const int r0 = bm0 + wr * (BM / 2) + 16 * i + lk * 4;
#pragma unroll
      for (int q = 0; q < 4; ++q) {
        float t = acc[i][j][q] + bt;
        t = fmaxf(t, NEG * t);
        out[(size_t)(r0 + q) * ldout + o] = (_Float16)t;
      }
    }
  }
}

// ---------------- edge max, standalone (O=128/256) ---------------------------
template <int O>
__global__ __launch_bounds__(256) void edge_max8(
    const _Float16* __restrict__ z, const int* __restrict__ idx,
    const float* __restrict__ betap, _Float16* __restrict__ out, int ldout) {
  constexpr int TPP = O / 8;
  constexpr int PPB = 256 / TPP;
  constexpr int NW = (K_ + TPP - 1) / TPP;
  const int t = threadIdx.x;
  const int batch = blockIdx.x & 7;
  const int chunk = blockIdx.x >> 3;
  const int p = (batch << 12) + chunk * PPB + t / TPP;
  const int lid = t % TPP;
  const int cb = lid * 8;
  const int* ip = idx + (size_t)p * K_;
  int ir[NW];
#pragma unroll
  for (int wv = 0; wv < NW; ++wv) {
    const int l = wv * TPP + lid;
    ir[wv] = (l < K_) ? ip[l] : ip[0];
  }
  const _Float16* zb = z + ((size_t)(batch << 12)) * O;

  f16x8 mx = *reinterpret_cast<const f16x8*>(zb + (size_t)__shfl(ir[0], 0, TPP) * O + cb);
#pragma unroll
  for (int k = 1; k < K_; ++k) {
    const int g = __shfl(ir[k / TPP], k % TPP, TPP);
    const f16x8 v = *reinterpret_cast<const f16x8*>(zb + (size_t)g * O + cb);
#pragma unroll
    for (int q = 0; q < 8; ++q) mx[q] = v[q] > mx[q] ? v[q] : mx[q];
  }
  const f16x8 vc = *reinterpret_cast<const f16x8*>(z + (size_t)p * O + cb);
  f16x8 vo;
#pragma unroll
  for (int q = 0; q < 8; ++q) {
    const float e = (float)mx[q] - (float)vc[q] + betap[cb + q];
    vo[q] = (_Float16)fmaxf(e, NEG * e);
  }
  *reinterpret_cast<f16x8*>(out + (size_t)p * ldout + cb) = vo;
}

// ---------------- launch -----------------------------------------------------
extern "C" void kernel_launch(void* const* d_in, const int* in_sizes, int n_in,
                              void* d_out, int out_size, void* d_ws, size_t ws_size,
                              hipStream_t stream) {
  const float* x  = (const float*)d_in[0];
  const int* idx  = (const int*)d_in[1];
  const float* w[7];
  for (int i = 0; i < 7; ++i) w[i] = (const float*)d_in[2 + i];
  const float* bn[24];
  for (int i = 0; i < 24; ++i) bn[i] = (const float*)d_in[9 + i];

  // ws: P@0 (32KB) | Wh@32KB (~0.42MB) | z_a@1MB (16MB) | h512@17MB (32MB) | z_b@49MB (16MB)
  float* P       = (float*)d_ws;
  _Float16* Wh   = (_Float16*)((char*)d_ws + (32 << 10));
  _Float16* z_a  = (_Float16*)((char*)d_ws + (1u << 20));
  _Float16* h512 = (_Float16*)((char*)d_ws + (17u << 20));
  _Float16* z_b  = (_Float16*)((char*)d_ws + (49u << 20));

  prep_c3<<<1329, 256, 0, stream>>>(
      x, w[0], w[1], w[2], w[3], w[4], w[5],
      bn[0], bn[1], bn[2], bn[3],   bn[4], bn[5], bn[6], bn[7],
      bn[8], bn[9], bn[10], bn[11], bn[12], bn[13], bn[14], bn[15],
      bn[16], bn[17], bn[18], bn[19], bn[20], bn[21], bn[22], bn[23],
      P, Wh, z_a);

  const float* bt1 = P + 64;
  const float* bt2 = P + 192;
  const float* bt3 = P + 384;
  const float* bt4 = P + 768;
  const float* bt5 = P + 1280;
  const float* bt6 = P + 1664;
  const _Float16* W2 = Wh + 0, *W3 = Wh + 4096, *W4 = Wh + 12288,
               *W5 = Wh + 45056, *W6 = Wh + 176128;

  // L1 edge + L2 GEMM fused: z1 -> (x1 -> h512+0, z2 -> z_b ld 64)
  edge_gemm64<64><<<M_ / 128, 256, 0, stream>>>(z_a, idx, bt1, W2, h512 + 0, z_b, 64);
  // L2 edge + L3 GEMM fused: z2 -> (x2 -> h512+64, z3 -> z_a ld 128)
  edge_gemm64<128><<<M_ / 128, 256, 0, stream>>>(z_b, idx, bt2, W3, h512 + 64, z_a, 128);
  // L3 edge: z3 -> x3 (h512+128)
  edge_max8<128><<<M_ / 16, 256, 0, stream>>>(z_a, idx, bt3, h512 + 128, 512);
  // L4 GEMM: x3 -> z4 (z_b ld 256)
  gemm_pipe<128, 128, 128, 0><<<dim3(M_ / 128, 2), 256, 0, stream>>>(
      h512 + 128, 512, W4, nullptr, z_b, 256);
  // L4 edge: z4 -> x4 (h512+256)
  edge_max8<256><<<M_ / 8, 256, 0, stream>>>(z_b, idx, bt4, h512 + 256, 512);
  // L5: pointconv(512 -> 256), 8-wave single-pass -> z_a ld 256
  gemm_pipe8<128, 256, 512, 1><<<M_ / 128, 512, 0, stream>>>(
      h512, 512, W5, bt5, z_a, 256, nullptr, nullptr);
  // L6+L7: pointconv(256 -> 128) fused with final 128 -> 1 + lrelu, 8-wave
  gemm_pipe8<128, 128, 256, 2><<<M_ / 128, 512, 0, stream>>>(
      z_a, 256, W6, bt6, nullptr, 0, w[6], (float*)d_out);
}